// Round 1
// baseline (13930.992 us; speedup 1.0000x reference)
//
#include <hip/hip_runtime.h>
#include <hip/hip_bf16.h>
#include <cstdint>
#include <cstddef>

#define GAT_H 8

__device__ __forceinline__ void atomAddF(float* p, float v) {
    unsafeAtomicAdd(p, v);   // global_atomic_add_f32 on gfx950
}

__device__ __forceinline__ void atomicMaxF(float* addr, float val) {
    // sign-split trick: int max for >=0, unsigned min for <0.
    if (val >= 0.0f) atomicMax((int*)addr, __float_as_int(val));
    else             atomicMin((unsigned int*)addr, __float_as_uint(val));
}

// ---------------- node matmul: Hout[n,c] = sum_k X[n,k] * W[k,c] ----------------
__global__ void matmul_kernel(const float* __restrict__ X, const float* __restrict__ W,
                              float* __restrict__ Hout, int D, int C) {
    extern __shared__ float xs[];
    const int n = blockIdx.x;
    const int c = threadIdx.x;            // blockDim.x == C
    for (int k = threadIdx.x; k < D; k += blockDim.x) xs[k] = X[(size_t)n * D + k];
    __syncthreads();
    float acc = 0.f;
    for (int k = 0; k < D; ++k) acc += xs[k] * W[(size_t)k * C + c];
    Hout[(size_t)n * C + c] = acc;
}

// ---------------- attention logits per (node, head) ----------------
__global__ void attnlogit_kernel(const float* __restrict__ Hf,
                                 const float* __restrict__ a_src,
                                 const float* __restrict__ a_dst,
                                 float* __restrict__ als, float* __restrict__ ald,
                                 int N, int F) {
    const int t = blockIdx.x * blockDim.x + threadIdx.x;
    if (t >= N * GAT_H) return;
    const int n = t / GAT_H, h = t % GAT_H;
    const float* hp = Hf + (size_t)n * GAT_H * F + h * F;
    float s1 = 0.f, s2 = 0.f;
    for (int f = 0; f < F; ++f) {
        const float v = hp[f];
        s1 += v * a_src[h * F + f];
        s2 += v * a_dst[h * F + f];
    }
    als[t] = s1; ald[t] = s2;
}

__global__ void init_ms_kernel(float* __restrict__ m, float* __restrict__ s, int n) {
    const int t = blockIdx.x * blockDim.x + threadIdx.x;
    if (t < n) { m[t] = -1e30f; s[t] = 0.f; }
}

// ---------------- edge pass A: segment max of leaky-relu logits into m[dst,h] ----------------
__global__ void edge_max_kernel(const int* __restrict__ ei,
                                const float* __restrict__ als, const float* __restrict__ ald,
                                float* __restrict__ m, int nE, int nN) {
    const int e = blockIdx.x * blockDim.x + threadIdx.x;
    if (e >= nE + nN) return;
    int src, dst;
    if (e < nE) { src = ei[e]; dst = ei[nE + e]; }
    else        { src = dst = e - nE; }            // self-loop
    #pragma unroll
    for (int h = 0; h < GAT_H; ++h) {
        float x = als[src * GAT_H + h] + ald[dst * GAT_H + h];
        x = x > 0.f ? x : 0.2f * x;                // leaky_relu(0.2)
        atomicMaxF(&m[dst * GAT_H + h], x);
    }
}

// ---------------- edge pass B: p=exp(e-m); s[dst,h]+=p; acc[dst,h,:]+=p*h[src,h,:] ----------------
__global__ void edge_acc_kernel(const int* __restrict__ ei,
                                const float* __restrict__ als, const float* __restrict__ ald,
                                const float* __restrict__ m, float* __restrict__ s,
                                const float* __restrict__ Hf, float* __restrict__ acc,
                                int nE, int nN, int F) {
    const long long t = (long long)blockIdx.x * blockDim.x + threadIdx.x;
    if (t >= (long long)(nE + nN) * GAT_H) return;
    const int e = (int)(t / GAT_H);
    const int h = (int)(t % GAT_H);
    int src, dst;
    if (e < nE) { src = ei[e]; dst = ei[nE + e]; }
    else        { src = dst = e - nE; }
    float x = als[src * GAT_H + h] + ald[dst * GAT_H + h];
    x = x > 0.f ? x : 0.2f * x;
    const float p = expf(x - m[dst * GAT_H + h]);
    atomAddF(&s[dst * GAT_H + h], p);
    const float* hp = Hf  + (size_t)src * GAT_H * F + h * F;
    float*       ap = acc + (size_t)dst * GAT_H * F + h * F;
    for (int f = 0; f < F; ++f) atomAddF(&ap[f], p * hp[f]);
}

// ---------------- finalize: out = elu(acc/(s+1e-16) + b) ----------------
__global__ void finalize_kernel(const float* __restrict__ acc, const float* __restrict__ s,
                                const float* __restrict__ b, float* __restrict__ out,
                                int N, int F) {
    const int t = blockIdx.x * blockDim.x + threadIdx.x;
    const int HF = GAT_H * F;
    if (t >= N * HF) return;
    const int n = t / HF, c = t % HF, h = c / F;
    const float v = acc[t] / (s[n * GAT_H + h] + 1e-16f) + b[c];
    out[t] = v > 0.f ? v : expm1f(v);
}

// ---------------- pooling: pooled[g,c] += A[n,c]; cnt[g] += 1 ----------------
__global__ void pool_kernel(const float* __restrict__ A, const int* __restrict__ batch,
                            float* __restrict__ pooled, float* __restrict__ cnt,
                            int N, int C) {
    const long long t = (long long)blockIdx.x * blockDim.x + threadIdx.x;
    if (t >= (long long)N * C) return;
    const int n = (int)(t / C), c = (int)(t % C);
    const int g = batch[n];
    atomAddF(&pooled[(size_t)g * C + c], A[t]);
    if (c == 0) atomAddF(&cnt[g], 1.f);
}

// ---------------- per-graph MLP: relu(pooled/cnt @ fc1 + b1) @ fc2 + b2 ----------------
__global__ void mlp_kernel(const float* __restrict__ pooled, const float* __restrict__ cnt,
                           const float* __restrict__ fc1w, const float* __restrict__ fc1b,
                           const float* __restrict__ fc2w, const float* __restrict__ fc2b,
                           float* __restrict__ out) {
    __shared__ float pl[128];
    __shared__ float red[32];
    const int g = blockIdx.x, j = threadIdx.x;   // 32 threads
    const float inv = 1.f / fmaxf(cnt[g], 1.f);
    for (int k = j; k < 128; k += 32) pl[k] = pooled[(size_t)g * 128 + k] * inv;
    __syncthreads();
    float a = fc1b[j];
    for (int k = 0; k < 128; ++k) a += pl[k] * fc1w[k * 32 + j];
    a = fmaxf(a, 0.f);
    red[j] = a * fc2w[j];
    __syncthreads();
    if (j == 0) {
        float sum = fc2b[0];
        for (int k = 0; k < 32; ++k) sum += red[k];
        out[g] = sum;
    }
}

extern "C" void kernel_launch(void* const* d_in, const int* in_sizes, int n_in,
                              void* d_out, int out_size, void* d_ws, size_t ws_size,
                              hipStream_t stream) {
    const float* x     = (const float*)d_in[0];
    const int*   ei    = (const int*)  d_in[1];
    const int*   batch = (const int*)  d_in[2];
    const float* W1 = (const float*)d_in[3],  *as1 = (const float*)d_in[4],
               *ad1 = (const float*)d_in[5],  *b1  = (const float*)d_in[6];
    const float* W2 = (const float*)d_in[7],  *as2 = (const float*)d_in[8],
               *ad2 = (const float*)d_in[9],  *b2  = (const float*)d_in[10];
    const float* W3 = (const float*)d_in[11], *as3 = (const float*)d_in[12],
               *ad3 = (const float*)d_in[13], *b3  = (const float*)d_in[14];
    const float* fc1w = (const float*)d_in[15], *fc1b = (const float*)d_in[16];
    const float* fc2w = (const float*)d_in[17], *fc2b = (const float*)d_in[18];

    const int N  = in_sizes[0] / 16;     // 50000
    const int NE = in_sizes[1] / 2;      // 800000
    const int NG = out_size;             // 256

    // workspace layout (floats)
    float* ws = (float*)d_ws;
    size_t off = 0;
    float* A   = ws + off; off += (size_t)N * 128;   // layer output / next input
    float* B   = ws + off; off += (size_t)N * 128;   // matmul result h
    float* Cc  = ws + off; off += (size_t)N * 128;   // weighted-sum accumulator
    float* als = ws + off; off += (size_t)N * GAT_H;
    float* ald = ws + off; off += (size_t)N * GAT_H;
    float* m   = ws + off; off += (size_t)N * GAT_H;
    float* s   = ws + off; off += (size_t)N * GAT_H;
    float* pooled = ws + off; off += (size_t)NG * 128;
    float* cnt    = ws + off; off += (size_t)NG;

    const int ET = NE + N;   // edges incl. self-loops

    auto run_layer = [&](const float* X, int D, int F,
                         const float* W, const float* asrc, const float* adst, const float* b) {
        const int HF = GAT_H * F;
        hipMemsetAsync(Cc, 0, (size_t)N * HF * sizeof(float), stream);
        init_ms_kernel<<<(N * GAT_H + 255) / 256, 256, 0, stream>>>(m, s, N * GAT_H);
        matmul_kernel<<<N, HF, D * sizeof(float), stream>>>(X, W, B, D, HF);
        attnlogit_kernel<<<(N * GAT_H + 255) / 256, 256, 0, stream>>>(B, asrc, adst, als, ald, N, F);
        edge_max_kernel<<<(ET + 255) / 256, 256, 0, stream>>>(ei, als, ald, m, NE, N);
        edge_acc_kernel<<<(int)(((long long)ET * GAT_H + 255) / 256), 256, 0, stream>>>(
            ei, als, ald, m, s, B, Cc, NE, N, F);
        finalize_kernel<<<(N * HF + 255) / 256, 256, 0, stream>>>(Cc, s, b, A, N, F);
    };

    run_layer(x, 16, 8,  W1, as1, ad1, b1);   // 16  -> 8x8  = 64
    run_layer(A, 64, 16, W2, as2, ad2, b2);   // 64  -> 8x16 = 128
    run_layer(A, 128,16, W3, as3, ad3, b3);   // 128 -> 8x16 = 128

    hipMemsetAsync(pooled, 0, ((size_t)NG * 128 + NG) * sizeof(float), stream);
    pool_kernel<<<(int)(((long long)N * 128 + 255) / 256), 256, 0, stream>>>(A, batch, pooled, cnt, N, 128);
    mlp_kernel<<<NG, 32, 0, stream>>>(pooled, cnt, fc1w, fc1b, fc2w, fc2b, (float*)d_out);
}

// Round 2
// 772.425 us; speedup vs baseline: 18.0354x; 18.0354x over previous
//
#include <hip/hip_runtime.h>
#include <hip/hip_bf16.h>
#include <cstdint>
#include <cstddef>

#define GAT_H 8

// ======================= CSR build (once per call) =======================

__global__ void hist_kernel(const int* __restrict__ ei, int* __restrict__ deg,
                            int nE, int nN) {
    const int e = blockIdx.x * blockDim.x + threadIdx.x;
    if (e >= nE + nN) return;
    const int dst = (e < nE) ? ei[nE + e] : (e - nE);   // self-loop tail
    atomicAdd(&deg[dst], 1);
}

// single-workgroup exclusive scan: rowptr[0]=0, rowptr[i+1]=sum(deg[0..i])
__global__ __launch_bounds__(1024) void scan_kernel(const int* __restrict__ deg,
                                                    int* __restrict__ rowptr, int N) {
    __shared__ int wsum[16];
    __shared__ int carry;
    const int tid = threadIdx.x;
    const int lane = tid & 63, wid = tid >> 6;
    if (tid == 0) carry = 0;
    __syncthreads();
    for (int base = 0; base < N; base += 1024) {
        const int i = base + tid;
        int incl = (i < N) ? deg[i] : 0;
        #pragma unroll
        for (int d = 1; d < 64; d <<= 1) {
            const int t = __shfl_up(incl, d, 64);
            if (lane >= d) incl += t;
        }
        if (lane == 63) wsum[wid] = incl;
        __syncthreads();
        if (tid == 0) {
            int run = carry;
            #pragma unroll
            for (int w = 0; w < 16; ++w) { const int t2 = wsum[w]; wsum[w] = run; run += t2; }
            carry = run;
        }
        __syncthreads();
        if (i < N) rowptr[i + 1] = wsum[wid] + incl;
        __syncthreads();   // protect wsum before next iteration
    }
    if (tid == 0) rowptr[0] = 0;
}

__global__ void copy_int_kernel(const int* __restrict__ a, int* __restrict__ b, int n) {
    const int i = blockIdx.x * blockDim.x + threadIdx.x;
    if (i < n) b[i] = a[i];
}

__global__ void scatter_kernel(const int* __restrict__ ei, int* __restrict__ woff,
                               int* __restrict__ esrc, int nE, int nN) {
    const int e = blockIdx.x * blockDim.x + threadIdx.x;
    if (e >= nE + nN) return;
    int src, dst;
    if (e < nE) { src = ei[e]; dst = ei[nE + e]; }
    else        { src = dst = e - nE; }
    const int pos = atomicAdd(&woff[dst], 1);
    esrc[pos] = src;
}

// ======================= node matmul (LDS-tiled, 32 nodes/block) =======================

template<int D, int C>
__global__ __launch_bounds__(256) void matmul_t(const float* __restrict__ X,
                                                const float* __restrict__ W,
                                                float* __restrict__ Hout, int N) {
    __shared__ float xs[32][D + 1];        // +1 pad: kills 8-way bank conflict
    const int n0 = blockIdx.x * 32;
    for (int idx = threadIdx.x; idx < 32 * D; idx += 256) {
        const int nn = idx / D, kk = idx % D;
        const int n = n0 + nn;
        xs[nn][kk] = (n < N) ? X[(size_t)n * D + kk] : 0.f;
    }
    __syncthreads();
    const int nl = threadIdx.x >> 3, cb = threadIdx.x & 7;
    constexpr int CPT = C / 8;
    float acc[CPT];
    #pragma unroll
    for (int j = 0; j < CPT; ++j) acc[j] = 0.f;
    for (int k = 0; k < D; ++k) {
        const float xv = xs[nl][k];
        const float* wr = W + (size_t)k * C + cb;
        #pragma unroll
        for (int j = 0; j < CPT; ++j) acc[j] += xv * wr[8 * j];
    }
    const int n = n0 + nl;
    if (n < N) {
        #pragma unroll
        for (int j = 0; j < CPT; ++j) Hout[(size_t)n * C + cb + 8 * j] = acc[j];
    }
}

// ======================= attention logits per (node, head) =======================

__global__ void attnlogit_kernel(const float* __restrict__ Hf,
                                 const float* __restrict__ a_src,
                                 const float* __restrict__ a_dst,
                                 float* __restrict__ als, float* __restrict__ ald,
                                 int N, int F) {
    const int t = blockIdx.x * blockDim.x + threadIdx.x;
    if (t >= N * GAT_H) return;
    const int n = t / GAT_H, h = t % GAT_H;
    const float* hp = Hf + ((size_t)n * GAT_H + h) * F;
    float s1 = 0.f, s2 = 0.f;
    for (int f = 0; f < F; ++f) {
        const float v = hp[f];
        s1 += v * a_src[h * F + f];
        s2 += v * a_dst[h * F + f];
    }
    als[t] = s1; ald[t] = s2;
}

// ======================= fused gather: online softmax + weighted sum + ELU =======================

template<int F>
__global__ void gat_gather(const int* __restrict__ rowptr, const int* __restrict__ esrc,
                           const float* __restrict__ als, const float* __restrict__ ald,
                           const float* __restrict__ Hf, const float* __restrict__ b,
                           float* __restrict__ out, int N) {
    const int t = blockIdx.x * blockDim.x + threadIdx.x;
    if (t >= N * GAT_H) return;
    const int dst = t >> 3, h = t & 7;
    const int beg = rowptr[dst], end = rowptr[dst + 1];
    const float adh = ald[t];
    float m = -1e30f, s = 0.f;
    float4 acc[F / 4];
    #pragma unroll
    for (int j = 0; j < F / 4; ++j) acc[j] = make_float4(0.f, 0.f, 0.f, 0.f);
    for (int i = beg; i < end; ++i) {
        const int src = esrc[i];
        float x = als[src * GAT_H + h] + adh;
        x = x > 0.f ? x : 0.2f * x;          // leaky_relu(0.2)
        float p;
        if (x > m) {                          // online-softmax rescale
            const float scale = __expf(m - x);
            s *= scale;
            #pragma unroll
            for (int j = 0; j < F / 4; ++j) {
                acc[j].x *= scale; acc[j].y *= scale;
                acc[j].z *= scale; acc[j].w *= scale;
            }
            m = x; p = 1.f;
        } else {
            p = __expf(x - m);
        }
        s += p;
        const float4* hp = reinterpret_cast<const float4*>(Hf + ((size_t)src * GAT_H + h) * F);
        #pragma unroll
        for (int j = 0; j < F / 4; ++j) {
            const float4 v = hp[j];
            acc[j].x += p * v.x; acc[j].y += p * v.y;
            acc[j].z += p * v.z; acc[j].w += p * v.w;
        }
    }
    const float inv = 1.f / (s + 1e-16f);
    #pragma unroll
    for (int j = 0; j < F / 4; ++j) {
        const float o[4] = {acc[j].x, acc[j].y, acc[j].z, acc[j].w};
        #pragma unroll
        for (int q = 0; q < 4; ++q) {
            const float val = o[q] * inv + b[h * F + 4 * j + q];
            out[((size_t)dst * GAT_H + h) * F + 4 * j + q] =
                val > 0.f ? val : expm1f(val);   // ELU
        }
    }
}

// ======================= pooling (sorted batch -> binary search) + MLP, fused =======================

__global__ __launch_bounds__(256) void pool_mlp_kernel(
        const float* __restrict__ A, const int* __restrict__ batch,
        const float* __restrict__ fc1w, const float* __restrict__ fc1b,
        const float* __restrict__ fc2w, const float* __restrict__ fc2b,
        float* __restrict__ out, int N) {
    const int g = blockIdx.x;
    // lower_bound(batch, g) and lower_bound(batch, g+1) on sorted batch
    int lo, hi;
    {
        int l = 0, h2 = N;
        while (l < h2) { const int mid = (l + h2) >> 1; if (batch[mid] < g) l = mid + 1; else h2 = mid; }
        lo = l;
        h2 = N;
        while (l < h2) { const int mid = (l + h2) >> 1; if (batch[mid] < g + 1) l = mid + 1; else h2 = mid; }
        hi = l;
    }
    __shared__ float part[256];
    __shared__ float pl[128];
    __shared__ float red2[32];
    const int tid = threadIdx.x;
    const int c = tid & 127, half = tid >> 7;
    float acc = 0.f;
    for (int n = lo + half; n < hi; n += 2) acc += A[(size_t)n * 128 + c];
    part[tid] = acc;
    __syncthreads();
    if (tid < 128) {
        const float tot = part[tid] + part[tid + 128];
        const float cntf = (float)(hi - lo);
        pl[tid] = tot / fmaxf(cntf, 1.f);
    }
    __syncthreads();
    if (tid < 32) {
        float a = fc1b[tid];
        for (int k = 0; k < 128; ++k) a += pl[k] * fc1w[k * 32 + tid];
        a = fmaxf(a, 0.f);
        red2[tid] = a * fc2w[tid];
    }
    __syncthreads();
    if (tid == 0) {
        float sum = fc2b[0];
        for (int k = 0; k < 32; ++k) sum += red2[k];
        out[g] = sum;
    }
}

// ======================= launch =======================

extern "C" void kernel_launch(void* const* d_in, const int* in_sizes, int n_in,
                              void* d_out, int out_size, void* d_ws, size_t ws_size,
                              hipStream_t stream) {
    const float* x     = (const float*)d_in[0];
    const int*   ei    = (const int*)  d_in[1];
    const int*   batch = (const int*)  d_in[2];
    const float* W1 = (const float*)d_in[3],  *as1 = (const float*)d_in[4],
               *ad1 = (const float*)d_in[5],  *b1  = (const float*)d_in[6];
    const float* W2 = (const float*)d_in[7],  *as2 = (const float*)d_in[8],
               *ad2 = (const float*)d_in[9],  *b2  = (const float*)d_in[10];
    const float* W3 = (const float*)d_in[11], *as3 = (const float*)d_in[12],
               *ad3 = (const float*)d_in[13], *b3  = (const float*)d_in[14];
    const float* fc1w = (const float*)d_in[15], *fc1b = (const float*)d_in[16];
    const float* fc2w = (const float*)d_in[17], *fc2b = (const float*)d_in[18];

    const int N  = in_sizes[0] / 16;     // 50000
    const int NE = in_sizes[1] / 2;      // 800000
    const int NG = out_size;             // 256
    const int ET = NE + N;               // edges incl. self-loops

    // workspace layout (4-byte elements)
    float* ws = (float*)d_ws;
    size_t off = 0;
    float* A    = ws + off; off += (size_t)N * 128;    // layer output / next input
    float* B    = ws + off; off += (size_t)N * 128;    // matmul result h
    float* als  = ws + off; off += (size_t)N * GAT_H;
    float* ald  = ws + off; off += (size_t)N * GAT_H;
    int* deg    = (int*)(ws + off); off += N;
    int* rowptr = (int*)(ws + off); off += N + 1;
    int* woff   = (int*)(ws + off); off += N;
    int* esrc   = (int*)(ws + off); off += ET;

    // ---- CSR build (graph is identical for all 3 layers) ----
    hipMemsetAsync(deg, 0, (size_t)N * sizeof(int), stream);
    hist_kernel<<<(ET + 255) / 256, 256, 0, stream>>>(ei, deg, NE, N);
    scan_kernel<<<1, 1024, 0, stream>>>(deg, rowptr, N);
    copy_int_kernel<<<(N + 255) / 256, 256, 0, stream>>>(rowptr, woff, N);
    scatter_kernel<<<(ET + 255) / 256, 256, 0, stream>>>(ei, woff, esrc, NE, N);

    const int NH = N * GAT_H;

    // ---- layer 1: 16 -> 8x8 ----
    matmul_t<16, 64><<<(N + 31) / 32, 256, 0, stream>>>(x, W1, B, N);
    attnlogit_kernel<<<(NH + 255) / 256, 256, 0, stream>>>(B, as1, ad1, als, ald, N, 8);
    gat_gather<8><<<(NH + 255) / 256, 256, 0, stream>>>(rowptr, esrc, als, ald, B, b1, A, N);

    // ---- layer 2: 64 -> 8x16 ----
    matmul_t<64, 128><<<(N + 31) / 32, 256, 0, stream>>>(A, W2, B, N);
    attnlogit_kernel<<<(NH + 255) / 256, 256, 0, stream>>>(B, as2, ad2, als, ald, N, 16);
    gat_gather<16><<<(NH + 255) / 256, 256, 0, stream>>>(rowptr, esrc, als, ald, B, b2, A, N);

    // ---- layer 3: 128 -> 8x16 ----
    matmul_t<128, 128><<<(N + 31) / 32, 256, 0, stream>>>(A, W3, B, N);
    attnlogit_kernel<<<(NH + 255) / 256, 256, 0, stream>>>(B, as3, ad3, als, ald, N, 16);
    gat_gather<16><<<(NH + 255) / 256, 256, 0, stream>>>(rowptr, esrc, als, ald, B, b3, A, N);

    // ---- pool + MLP ----
    pool_mlp_kernel<<<NG, 256, 0, stream>>>(A, batch, fc1w, fc1b, fc2w, fc2b,
                                            (float*)d_out, N);
}

// Round 3
// 556.681 us; speedup vs baseline: 25.0251x; 1.3876x over previous
//
#include <hip/hip_runtime.h>
#include <hip/hip_bf16.h>
#include <cstdint>
#include <cstddef>

#define GAT_H 8

// ======================= CSR build (once per call) =======================

__global__ void hist_kernel(const int* __restrict__ ei, int* __restrict__ deg,
                            int nE, int nN) {
    const int e = blockIdx.x * blockDim.x + threadIdx.x;
    if (e >= nE + nN) return;
    const int dst = (e < nE) ? ei[nE + e] : (e - nE);   // self-loop tail
    atomicAdd(&deg[dst], 1);
}

// single-workgroup exclusive scan: rowptr[0]=0, rowptr[i+1]=sum(deg[0..i])
__global__ __launch_bounds__(1024) void scan_kernel(const int* __restrict__ deg,
                                                    int* __restrict__ rowptr, int N) {
    __shared__ int wsum[16];
    __shared__ int carry;
    const int tid = threadIdx.x;
    const int lane = tid & 63, wid = tid >> 6;
    if (tid == 0) carry = 0;
    __syncthreads();
    for (int base = 0; base < N; base += 1024) {
        const int i = base + tid;
        int incl = (i < N) ? deg[i] : 0;
        #pragma unroll
        for (int d = 1; d < 64; d <<= 1) {
            const int t = __shfl_up(incl, d, 64);
            if (lane >= d) incl += t;
        }
        if (lane == 63) wsum[wid] = incl;
        __syncthreads();
        if (tid == 0) {
            int run = carry;
            #pragma unroll
            for (int w = 0; w < 16; ++w) { const int t2 = wsum[w]; wsum[w] = run; run += t2; }
            carry = run;
        }
        __syncthreads();
        if (i < N) rowptr[i + 1] = wsum[wid] + incl;
        __syncthreads();   // protect wsum before next iteration
    }
    if (tid == 0) rowptr[0] = 0;
}

__global__ void copy_int_kernel(const int* __restrict__ a, int* __restrict__ b, int n) {
    const int i = blockIdx.x * blockDim.x + threadIdx.x;
    if (i < n) b[i] = a[i];
}

__global__ void scatter_kernel(const int* __restrict__ ei, int* __restrict__ woff,
                               int* __restrict__ esrc, int nE, int nN) {
    const int e = blockIdx.x * blockDim.x + threadIdx.x;
    if (e >= nE + nN) return;
    int src, dst;
    if (e < nE) { src = ei[e]; dst = ei[nE + e]; }
    else        { src = dst = e - nE; }
    const int pos = atomicAdd(&woff[dst], 1);
    esrc[pos] = src;
}

// ======================= node matmul (register-blocked, LDS-staged) =======================
// 64-node x C-col tile per 256-thread block; K staged in chunks of KK.
// Thread layout: cg = tid % (C/8) owns 8 contiguous cols; ng = tid / (C/8) owns
// NPT = 64/(256/(C/8)) nodes. Per 4-k-step: 12 ds_read_b128 vs 128 FMAs.
template<int D, int C, int KK>
__global__ __launch_bounds__(256) void matmul_tile(const float* __restrict__ X,
                                                   const float* __restrict__ W,
                                                   float* __restrict__ Hout, int N) {
    constexpr int CG  = C / 8;          // col-groups of 8
    constexpr int NGR = 256 / CG;       // node-groups
    constexpr int NPT = 64 / NGR;       // nodes per thread
    constexpr int XS  = KK + 4;         // padded x-row stride (keeps 16B align, skews banks)
    __shared__ float xs[64][XS];
    __shared__ float wsh[KK][C];

    const int n0 = blockIdx.x * 64;
    const int tid = threadIdx.x;
    const int cg = tid % CG, ngr = tid / CG;
    const int c0 = cg * 8;

    float acc[NPT][8];
    #pragma unroll
    for (int i = 0; i < NPT; ++i)
        #pragma unroll
        for (int j = 0; j < 8; ++j) acc[i][j] = 0.f;

    for (int k0 = 0; k0 < D; k0 += KK) {
        // stage X tile (64 x KK) as float4
        for (int t = tid; t < 64 * (KK / 4); t += 256) {
            const int row = t / (KK / 4), c4 = (t % (KK / 4)) * 4;
            const int n = n0 + row;
            float4 v = make_float4(0.f, 0.f, 0.f, 0.f);
            if (n < N) v = *reinterpret_cast<const float4*>(&X[(size_t)n * D + k0 + c4]);
            *reinterpret_cast<float4*>(&xs[row][c4]) = v;
        }
        // stage W chunk (KK x C) as float4
        for (int t = tid; t < KK * (C / 4); t += 256) {
            const int row = t / (C / 4), c4 = (t % (C / 4)) * 4;
            *reinterpret_cast<float4*>(&wsh[row][c4]) =
                *reinterpret_cast<const float4*>(&W[(size_t)(k0 + row) * C + c4]);
        }
        __syncthreads();

        #pragma unroll
        for (int k4 = 0; k4 < KK; k4 += 4) {
            float4 xv[NPT];
            #pragma unroll
            for (int i = 0; i < NPT; ++i)
                xv[i] = *reinterpret_cast<const float4*>(&xs[ngr * NPT + i][k4]);
            #pragma unroll
            for (int kk = 0; kk < 4; ++kk) {
                const float4 w0 = *reinterpret_cast<const float4*>(&wsh[k4 + kk][c0]);
                const float4 w1 = *reinterpret_cast<const float4*>(&wsh[k4 + kk][c0 + 4]);
                #pragma unroll
                for (int i = 0; i < NPT; ++i) {
                    const float xk = (kk == 0) ? xv[i].x : (kk == 1) ? xv[i].y
                                   : (kk == 2) ? xv[i].z : xv[i].w;
                    acc[i][0] += xk * w0.x; acc[i][1] += xk * w0.y;
                    acc[i][2] += xk * w0.z; acc[i][3] += xk * w0.w;
                    acc[i][4] += xk * w1.x; acc[i][5] += xk * w1.y;
                    acc[i][6] += xk * w1.z; acc[i][7] += xk * w1.w;
                }
            }
        }
        __syncthreads();
    }

    #pragma unroll
    for (int i = 0; i < NPT; ++i) {
        const int n = n0 + ngr * NPT + i;
        if (n < N) {
            float4 o0 = make_float4(acc[i][0], acc[i][1], acc[i][2], acc[i][3]);
            float4 o1 = make_float4(acc[i][4], acc[i][5], acc[i][6], acc[i][7]);
            *reinterpret_cast<float4*>(&Hout[(size_t)n * C + c0])     = o0;
            *reinterpret_cast<float4*>(&Hout[(size_t)n * C + c0 + 4]) = o1;
        }
    }
}

// ======================= attention logits per (node, head) =======================

__global__ void attnlogit_kernel(const float* __restrict__ Hf,
                                 const float* __restrict__ a_src,
                                 const float* __restrict__ a_dst,
                                 float* __restrict__ als, float* __restrict__ ald,
                                 int N, int F) {
    const int t = blockIdx.x * blockDim.x + threadIdx.x;
    if (t >= N * GAT_H) return;
    const int n = t / GAT_H, h = t % GAT_H;
    const float* hp = Hf + ((size_t)n * GAT_H + h) * F;
    float s1 = 0.f, s2 = 0.f;
    for (int f = 0; f < F; ++f) {
        const float v = hp[f];
        s1 += v * a_src[h * F + f];
        s2 += v * a_dst[h * F + f];
    }
    als[t] = s1; ald[t] = s2;
}

// ======================= fused gather: online softmax + weighted sum + ELU =======================

template<int F>
__global__ void gat_gather(const int* __restrict__ rowptr, const int* __restrict__ esrc,
                           const float* __restrict__ als, const float* __restrict__ ald,
                           const float* __restrict__ Hf, const float* __restrict__ b,
                           float* __restrict__ out, int N) {
    const int t = blockIdx.x * blockDim.x + threadIdx.x;
    if (t >= N * GAT_H) return;
    const int dst = t >> 3, h = t & 7;
    const int beg = rowptr[dst], end = rowptr[dst + 1];
    const float adh = ald[t];
    float m = -1e30f, s = 0.f;
    float4 acc[F / 4];
    #pragma unroll
    for (int j = 0; j < F / 4; ++j) acc[j] = make_float4(0.f, 0.f, 0.f, 0.f);
    for (int i = beg; i < end; ++i) {
        const int src = esrc[i];
        float x = als[src * GAT_H + h] + adh;
        x = x > 0.f ? x : 0.2f * x;          // leaky_relu(0.2)
        float p;
        if (x > m) {                          // online-softmax rescale
            const float scale = __expf(m - x);
            s *= scale;
            #pragma unroll
            for (int j = 0; j < F / 4; ++j) {
                acc[j].x *= scale; acc[j].y *= scale;
                acc[j].z *= scale; acc[j].w *= scale;
            }
            m = x; p = 1.f;
        } else {
            p = __expf(x - m);
        }
        s += p;
        const float4* hp = reinterpret_cast<const float4*>(Hf + ((size_t)src * GAT_H + h) * F);
        #pragma unroll
        for (int j = 0; j < F / 4; ++j) {
            const float4 v = hp[j];
            acc[j].x += p * v.x; acc[j].y += p * v.y;
            acc[j].z += p * v.z; acc[j].w += p * v.w;
        }
    }
    const float inv = 1.f / (s + 1e-16f);
    #pragma unroll
    for (int j = 0; j < F / 4; ++j) {
        const float o[4] = {acc[j].x, acc[j].y, acc[j].z, acc[j].w};
        #pragma unroll
        for (int q = 0; q < 4; ++q) {
            const float val = o[q] * inv + b[h * F + 4 * j + q];
            out[((size_t)dst * GAT_H + h) * F + 4 * j + q] =
                val > 0.f ? val : expm1f(val);   // ELU
        }
    }
}

// ======================= pooling (sorted batch -> binary search) + MLP, fused =======================

__global__ __launch_bounds__(256) void pool_mlp_kernel(
        const float* __restrict__ A, const int* __restrict__ batch,
        const float* __restrict__ fc1w, const float* __restrict__ fc1b,
        const float* __restrict__ fc2w, const float* __restrict__ fc2b,
        float* __restrict__ out, int N) {
    const int g = blockIdx.x;
    int lo, hi;
    {
        int l = 0, h2 = N;
        while (l < h2) { const int mid = (l + h2) >> 1; if (batch[mid] < g) l = mid + 1; else h2 = mid; }
        lo = l;
        h2 = N;
        while (l < h2) { const int mid = (l + h2) >> 1; if (batch[mid] < g + 1) l = mid + 1; else h2 = mid; }
        hi = l;
    }
    __shared__ float part[256];
    __shared__ float pl[128];
    __shared__ float red2[32];
    const int tid = threadIdx.x;
    const int c = tid & 127, half = tid >> 7;
    float acc = 0.f;
    for (int n = lo + half; n < hi; n += 2) acc += A[(size_t)n * 128 + c];
    part[tid] = acc;
    __syncthreads();
    if (tid < 128) {
        const float tot = part[tid] + part[tid + 128];
        const float cntf = (float)(hi - lo);
        pl[tid] = tot / fmaxf(cntf, 1.f);
    }
    __syncthreads();
    if (tid < 32) {
        float a = fc1b[tid];
        for (int k = 0; k < 128; ++k) a += pl[k] * fc1w[k * 32 + tid];
        a = fmaxf(a, 0.f);
        red2[tid] = a * fc2w[tid];
    }
    __syncthreads();
    if (tid == 0) {
        float sum = fc2b[0];
        for (int k = 0; k < 32; ++k) sum += red2[k];
        out[g] = sum;
    }
}

// ======================= launch =======================

extern "C" void kernel_launch(void* const* d_in, const int* in_sizes, int n_in,
                              void* d_out, int out_size, void* d_ws, size_t ws_size,
                              hipStream_t stream) {
    const float* x     = (const float*)d_in[0];
    const int*   ei    = (const int*)  d_in[1];
    const int*   batch = (const int*)  d_in[2];
    const float* W1 = (const float*)d_in[3],  *as1 = (const float*)d_in[4],
               *ad1 = (const float*)d_in[5],  *b1  = (const float*)d_in[6];
    const float* W2 = (const float*)d_in[7],  *as2 = (const float*)d_in[8],
               *ad2 = (const float*)d_in[9],  *b2  = (const float*)d_in[10];
    const float* W3 = (const float*)d_in[11], *as3 = (const float*)d_in[12],
               *ad3 = (const float*)d_in[13], *b3  = (const float*)d_in[14];
    const float* fc1w = (const float*)d_in[15], *fc1b = (const float*)d_in[16];
    const float* fc2w = (const float*)d_in[17], *fc2b = (const float*)d_in[18];

    const int N  = in_sizes[0] / 16;     // 50000
    const int NE = in_sizes[1] / 2;      // 800000
    const int NG = out_size;             // 256
    const int ET = NE + N;               // edges incl. self-loops

    // workspace layout (4-byte elements)
    float* ws = (float*)d_ws;
    size_t off = 0;
    float* A    = ws + off; off += (size_t)N * 128;    // layer output / next input
    float* B    = ws + off; off += (size_t)N * 128;    // matmul result h
    float* als  = ws + off; off += (size_t)N * GAT_H;
    float* ald  = ws + off; off += (size_t)N * GAT_H;
    int* deg    = (int*)(ws + off); off += N;
    int* rowptr = (int*)(ws + off); off += N + 1;
    int* woff   = (int*)(ws + off); off += N;
    int* esrc   = (int*)(ws + off); off += ET;

    // ---- CSR build (graph is identical for all 3 layers) ----
    hipMemsetAsync(deg, 0, (size_t)N * sizeof(int), stream);
    hist_kernel<<<(ET + 255) / 256, 256, 0, stream>>>(ei, deg, NE, N);
    scan_kernel<<<1, 1024, 0, stream>>>(deg, rowptr, N);
    copy_int_kernel<<<(N + 255) / 256, 256, 0, stream>>>(rowptr, woff, N);
    scatter_kernel<<<(ET + 255) / 256, 256, 0, stream>>>(ei, woff, esrc, NE, N);

    const int NH = N * GAT_H;
    const int NB = (N + 63) / 64;

    // ---- layer 1: 16 -> 8x8 ----
    matmul_tile<16, 64, 16><<<NB, 256, 0, stream>>>(x, W1, B, N);
    attnlogit_kernel<<<(NH + 255) / 256, 256, 0, stream>>>(B, as1, ad1, als, ald, N, 8);
    gat_gather<8><<<(NH + 255) / 256, 256, 0, stream>>>(rowptr, esrc, als, ald, B, b1, A, N);

    // ---- layer 2: 64 -> 8x16 ----
    matmul_tile<64, 128, 32><<<NB, 256, 0, stream>>>(A, W2, B, N);
    attnlogit_kernel<<<(NH + 255) / 256, 256, 0, stream>>>(B, as2, ad2, als, ald, N, 16);
    gat_gather<16><<<(NH + 255) / 256, 256, 0, stream>>>(rowptr, esrc, als, ald, B, b2, A, N);

    // ---- layer 3: 128 -> 8x16 ----
    matmul_tile<128, 128, 32><<<NB, 256, 0, stream>>>(A, W3, B, N);
    attnlogit_kernel<<<(NH + 255) / 256, 256, 0, stream>>>(B, as3, ad3, als, ald, N, 16);
    gat_gather<16><<<(NH + 255) / 256, 256, 0, stream>>>(rowptr, esrc, als, ald, B, b3, A, N);

    // ---- pool + MLP ----
    pool_mlp_kernel<<<NG, 256, 0, stream>>>(A, batch, fc1w, fc1b, fc2w, fc2b,
                                            (float*)d_out, N);
}